// Round 3
// baseline (126.221 us; speedup 1.0000x reference)
//
#include <hip/hip_runtime.h>
#include <math.h>

typedef unsigned short u16;
typedef __attribute__((ext_vector_type(8))) short frag_ab;  // 8 bf16
typedef __attribute__((ext_vector_type(4))) float frag_cd;  // 4 fp32

#define BATCH 8
#define NN 128
#define FS 128
#define FV 64
#define NB 8
#define HID 64
#define ROUT 320
#define HSTRB 72    // hid bf16 LDS row stride (shorts)

// ---- ws layout (float offsets); s:[b][f][n], V:[b][f*3+c3][n], t:[b][g][n] ----
#define SZ_S (BATCH*FS*NN)
#define SZ_V (BATCH*FV*3*NN)
#define SZ_T (BATCH*FV*NN)
#define N_W2B (ROUT*HID)            // ushort count (layer-1 Wr2 in bf16)
#define OFF_SB 0
#define OFF_VB (OFF_SB+SZ_S)
#define OFF_T1 (OFF_VB+SZ_V)
#define OFF_W2B (OFF_T1+SZ_T)

__device__ __forceinline__ float silu_f(float x){ return x * (1.0f/(1.0f + __expf(-x))); }

__device__ __forceinline__ u16 f2bf(float x){
  union { float f; unsigned int u; } v; v.f = x;
  unsigned int r = v.u + 0x7fffu + ((v.u >> 16) & 1u);
  return (u16)(r >> 16);
}
__device__ __forceinline__ float bf2f(u16 h){
  union { unsigned int u; float f; } v; v.u = ((unsigned int)h) << 16; return v.f;
}

// ---------------- Layer 0 (specialized): TWO receivers per block ----------------
// R18: all scalar LDS loops vectorized (u32 colsum, float4 colsum/aggS/dV/sNew
// reads); dV transposed to [c3*68+f]; tOut split 4-way over 256 threads.
__global__ __launch_bounds__(512) void layer0_kernel(
    const float* __restrict__ pos,
    const float* __restrict__ species,  // (128)
    const float* __restrict__ Wr1l,     // (8,64) layer0
    const float* __restrict__ Wr2,      // (2,64,320) fp32
    const float* __restrict__ Wsv,      // (2,128,64)
    const float* __restrict__ WmixSl,   // (192,128) layer0
    const float* __restrict__ WmixVl,   // (128,64) layer0
    float* __restrict__ sOut,           // [b][f][n]
    float* __restrict__ vOut,           // [b][f*3+c3][n]
    float* __restrict__ tOut,           // [b][g][n]
    u16*   __restrict__ w2b)            // (320,64) bf16 c-major, layer1
{
  const int tid = threadIdx.x;
  const int b   = blockIdx.x >> 6;
  const int k0  = (blockIdx.x & 63) * 2;

  __shared__ u16   hidB[2][128*HSTRB];
  __shared__ float vhx[2][128], vhy[2][128], vhz[2][128];
  __shared__ float colsum[2][4][64];
  __shared__ float aggS[2][128];
  __shared__ float dV[2][204];          // [kk][c3*68+f]
  __shared__ float sNew[2][128];
  __shared__ float t0L[64];
  __shared__ float tPart[4][2][64];

  const float* pb   = pos + b*NN*3;
  const float* Wr2l = Wr2;

  {
    const int kk   = tid >> 8;
    const int r2   = tid & 255;
    const int i    = r2 & 127;
    const int half = r2 >> 7;
    const int k    = k0 + kk;
    float vx = pb[k*3+0]-pb[i*3+0];
    float vy = pb[k*3+1]-pb[i*3+1];
    float vz = pb[k*3+2]-pb[i*3+2];
    float r = sqrtf(vx*vx+vy*vy+vz*vz) + 1e-8f;
    float inv = 1.0f/r;
    if (half==0){ vhx[kk][i]=vx*inv; vhy[kk][i]=vy*inv; vhz[kk][i]=vz*inv; }
    float u = r*0.2f;
    float env = 0.0f;
    if (u < 1.0f && i != k){
      float u2=u*u, u6=u2*u2*u2;
      env = 1.0f - 28.0f*u6 + 48.0f*u6*u - 21.0f*u6*u2;
    }
    float coef = 0.6324555320336759f * inv * env;
    float th   = r * 0.6283185307179586f;
    float s1 = __sinf(th), c1 = __cosf(th);
    float rb[NB];
    rb[0] = coef*s1;
    float twoc = 2.f*c1, sp = s1, spp = 0.f;
    #pragma unroll
    for(int n=1;n<NB;n++){ float s = twoc*sp - spp; spp = sp; sp = s; rb[n] = coef*s; }
    u16* hrow = hidB[kk] + i*HSTRB;
    #pragma unroll
    for(int jg=0;jg<8;jg++){
      const int jgg = half*8 + jg;
      float h0=0.f,h1=0.f,h2=0.f,h3=0.f;
      #pragma unroll
      for(int n=0;n<NB;n++){
        const float* wr = Wr1l + n*HID + jgg*4;
        float rn = rb[n];
        h0 = fmaf(rn, wr[0], h0);
        h1 = fmaf(rn, wr[1], h1);
        h2 = fmaf(rn, wr[2], h2);
        h3 = fmaf(rn, wr[3], h3);
      }
      ushort4 uu = make_ushort4(f2bf(silu_f(h0)), f2bf(silu_f(h1)),
                                f2bf(silu_f(h2)), f2bf(silu_f(h3)));
      *(ushort4*)(hrow + jgg*4) = uu;
    }
  }
  __syncthreads();

  // ---- colsum: u32-paired columns, 256 active threads ----
  if (tid < 256){
    const int kk = tid >> 7;
    const int var = (tid >> 5) & 3;
    const int jh  = tid & 31;
    const u16* hb = hidB[kk] + 2*jh;
    float a0=0.f,a1=0.f,c0_=0.f,c1_=0.f;
    if (var == 0){
      #pragma unroll 8
      for (int i=0;i<128;i+=2){
        unsigned int v0 = *(const unsigned int*)(hb + i*HSTRB);
        unsigned int v1 = *(const unsigned int*)(hb + (i+1)*HSTRB);
        a0  += bf2f((u16)(v0 & 0xffffu)); a1  += bf2f((u16)(v0 >> 16));
        c0_ += bf2f((u16)(v1 & 0xffffu)); c1_ += bf2f((u16)(v1 >> 16));
      }
    } else {
      const float* wv = (var==1) ? vhx[kk] : (var==2) ? vhy[kk] : vhz[kk];
      #pragma unroll 8
      for (int i=0;i<128;i+=2){
        unsigned int v0 = *(const unsigned int*)(hb + i*HSTRB);
        unsigned int v1 = *(const unsigned int*)(hb + (i+1)*HSTRB);
        float w0 = wv[i], w1 = wv[i+1];
        a0  = fmaf(bf2f((u16)(v0 & 0xffffu)), w0, a0);
        a1  = fmaf(bf2f((u16)(v0 >> 16)),     w0, a1);
        c0_ = fmaf(bf2f((u16)(v1 & 0xffffu)), w1, c0_);
        c1_ = fmaf(bf2f((u16)(v1 >> 16)),     w1, c1_);
      }
    }
    colsum[kk][var][2*jh]   = a0+c0_;
    colsum[kk][var][2*jh+1] = a1+c1_;
  }
  __syncthreads();

  if (tid < 128){
    const int c = tid;
    float d0=0.f, d1=0.f;
    #pragma unroll 2
    for (int j0=0;j0<HID;j0+=4){
      float4 s0 = *(const float4*)&colsum[0][0][j0];
      float4 s1 = *(const float4*)&colsum[1][0][j0];
      float w0 = Wr2l[j0*ROUT + c];
      float w1 = Wr2l[(j0+1)*ROUT + c];
      float w2 = Wr2l[(j0+2)*ROUT + c];
      float w3 = Wr2l[(j0+3)*ROUT + c];
      d0 = fmaf(s0.x,w0,d0); d0 = fmaf(s0.y,w1,d0); d0 = fmaf(s0.z,w2,d0); d0 = fmaf(s0.w,w3,d0);
      d1 = fmaf(s1.x,w0,d1); d1 = fmaf(s1.y,w1,d1); d1 = fmaf(s1.z,w2,d1); d1 = fmaf(s1.w,w3,d1);
    }
    float sc = species[c] * (1.0f/128.0f);
    aggS[0][c] = sc * d0;
    aggS[1][c] = sc * d1;
  } else if (tid < 320){
    const int o = tid - 128;
    const int f = o & 63, c3 = o >> 6;
    float d0=0.f, d1=0.f;
    #pragma unroll 2
    for (int j0=0;j0<HID;j0+=4){
      float4 s0 = *(const float4*)&colsum[0][1+c3][j0];
      float4 s1 = *(const float4*)&colsum[1][1+c3][j0];
      float w0 = Wr2l[j0*ROUT + 192 + f];
      float w1 = Wr2l[(j0+1)*ROUT + 192 + f];
      float w2 = Wr2l[(j0+2)*ROUT + 192 + f];
      float w3 = Wr2l[(j0+3)*ROUT + 192 + f];
      d0 = fmaf(s0.x,w0,d0); d0 = fmaf(s0.y,w1,d0); d0 = fmaf(s0.z,w2,d0); d0 = fmaf(s0.w,w3,d0);
      d1 = fmaf(s1.x,w0,d1); d1 = fmaf(s1.y,w1,d1); d1 = fmaf(s1.z,w2,d1); d1 = fmaf(s1.w,w3,d1);
    }
    dV[0][c3*68+f] = d0 * (1.0f/128.0f);
    dV[1][c3*68+f] = d1 * (1.0f/128.0f);
  } else if (tid < 384){
    const int g = tid - 320;
    float a0=0.f, a1=0.f;
    #pragma unroll 8
    for (int c=0; c<FS; c+=2){
      a0 = fmaf(species[c],   Wsv[c*FV+g],     a0);
      a1 = fmaf(species[c+1], Wsv[(c+1)*FV+g], a1);
    }
    t0L[g] = a0+a1;
  } else if (tid < 424){
    const int t = blockIdx.x*40 + (tid-384);
    const int j = t & 63, c = t >> 6;
    w2b[t] = f2bf(Wr2[HID*ROUT + j*ROUT + c]);
  }
  __syncthreads();

  if (tid < FS){
    float a0=0.f, a1=0.f;
    #pragma unroll 2
    for (int c0=0; c0<128; c0+=4){
      float4 g0 = *(const float4*)&aggS[0][c0];
      float4 g1 = *(const float4*)&aggS[1][c0];
      float w0 = WmixSl[c0*FS+tid];
      float w1 = WmixSl[(c0+1)*FS+tid];
      float w2 = WmixSl[(c0+2)*FS+tid];
      float w3 = WmixSl[(c0+3)*FS+tid];
      a0 = fmaf(g0.x,w0,a0); a0 = fmaf(g0.y,w1,a0); a0 = fmaf(g0.z,w2,a0); a0 = fmaf(g0.w,w3,a0);
      a1 = fmaf(g1.x,w0,a1); a1 = fmaf(g1.y,w1,a1); a1 = fmaf(g1.z,w2,a1); a1 = fmaf(g1.w,w3,a1);
    }
    float sn0 = species[tid] + silu_f(a0);
    float sn1 = species[tid] + silu_f(a1);
    sNew[0][tid] = sn0;
    sNew[1][tid] = sn1;
    sOut[(b*FS+tid)*NN + k0]     = sn0;
    sOut[(b*FS+tid)*NN + k0 + 1] = sn1;
  } else if (tid < 320){
    const int o = tid - 128;
    const int g = o/3, c3 = o - g*3;
    float a0=0.f, a1=0.f;
    #pragma unroll 2
    for (int f0=0; f0<FV; f0+=4){
      float4 dv0 = *(const float4*)&dV[0][c3*68+f0];
      float4 dv1 = *(const float4*)&dV[1][c3*68+f0];
      float4 t4  = *(const float4*)&t0L[f0];
      float w0 = WmixVl[f0*FV+g];
      float w1 = WmixVl[(f0+1)*FV+g];
      float w2 = WmixVl[(f0+2)*FV+g];
      float w3 = WmixVl[(f0+3)*FV+g];
      a0 = fmaf(t4.x*dv0.x, w0, a0); a0 = fmaf(t4.y*dv0.y, w1, a0);
      a0 = fmaf(t4.z*dv0.z, w2, a0); a0 = fmaf(t4.w*dv0.w, w3, a0);
      a1 = fmaf(t4.x*dv1.x, w0, a1); a1 = fmaf(t4.y*dv1.y, w1, a1);
      a1 = fmaf(t4.z*dv1.z, w2, a1); a1 = fmaf(t4.w*dv1.w, w3, a1);
    }
    vOut[(b*FV*3 + o)*NN + k0]     = a0;
    vOut[(b*FV*3 + o)*NN + k0 + 1] = a1;
  }
  __syncthreads();

  // ---- tOut: 4-way f-partials over 256 threads, then combine ----
  if (tid < 256){
    const int g = tid & 63, p = tid >> 6;
    const float* Wsv1 = Wsv + FS*FV;
    const int f0 = p*32;
    float a0=0.f, a1=0.f;
    #pragma unroll 2
    for (int f=f0; f<f0+32; f+=4){
      float4 s0 = *(const float4*)&sNew[0][f];
      float4 s1 = *(const float4*)&sNew[1][f];
      float w0 = Wsv1[f*FV+g];
      float w1 = Wsv1[(f+1)*FV+g];
      float w2 = Wsv1[(f+2)*FV+g];
      float w3 = Wsv1[(f+3)*FV+g];
      a0 = fmaf(s0.x,w0,a0); a0 = fmaf(s0.y,w1,a0); a0 = fmaf(s0.z,w2,a0); a0 = fmaf(s0.w,w3,a0);
      a1 = fmaf(s1.x,w0,a1); a1 = fmaf(s1.y,w1,a1); a1 = fmaf(s1.z,w2,a1); a1 = fmaf(s1.w,w3,a1);
    }
    tPart[p][0][g] = a0; tPart[p][1][g] = a1;
  }
  __syncthreads();
  if (tid < 128){
    const int g = tid & 63, kk = tid >> 6;
    tOut[(b*FV+g)*NN + k0 + kk] =
        tPart[0][kk][g] + tPart[1][kk][g] + tPart[2][kk][g] + tPart[3][kk][g];
  }
}

// ---------------- Layer 1 (final): FOUR receivers per block ----------------
// R17: 1024 threads, group-split MFMA. R18: E-phases vectorized; vector
// aggregates transposed to [c3*68+f] so V-mix/out_v read float4 over f.
__global__ __launch_bounds__(1024) void layer_kernel(
    const float* __restrict__ pos,
    const float* __restrict__ sIn,    // [b][f][n]
    const float* __restrict__ vIn,    // [b][f*3+c3][n]
    const float* __restrict__ tIn,    // [b][g][n]
    const float* __restrict__ Wr1l,   // (8,64) layer1
    const u16*   __restrict__ w2bl,   // (320,64) bf16, c-major
    const float* __restrict__ WmixSl, // (192,128)
    const float* __restrict__ WmixVl, // (128,64)
    const float* __restrict__ WoutS,
    const float* __restrict__ WoutV,
    float* __restrict__ outp)
{
  const int tid  = threadIdx.x;
  const int b    = blockIdx.x >> 5;
  const int k0   = (blockIdx.x & 31) * 4;     // receivers k0..k0+3
  const int w    = tid >> 6;                  // 0..15
  const int lane = tid & 63;
  const int col  = lane & 15;
  const int quad = lane >> 4;
  const int gh   = w & 1;                     // group half
  const int wq   = (w >> 1) & 3;              // column group
  const int sh   = w >> 3;                    // i-range half

  __shared__ u16   hidB[4][128*HSTRB];        // 73.7 KB
  __shared__ float vhx[4][128], vhy[4][128], vhz[4][128];
  __shared__ float aggP[4][2][600];           // scalar 0..191; vec [192/396 + c3*68 + f]
  __shared__ float sPart[4][4][FS];
  __shared__ float sNew[4][FS];
  __shared__ float vNewL[4][204];             // [kk][c3*68+g]
  __shared__ float comL[3];

  const float* pb = pos + b*NN*3;

  // ---- phase 0: tid = (jh, kk, i); half hid row per thread ----
  {
    const int jh = tid >> 9;        // 0..1: which half of the hid row
    const int kk = (tid >> 7) & 3;
    const int i  = tid & 127;
    const int k  = k0 + kk;
    float vx = pb[k*3+0]-pb[i*3+0];
    float vy = pb[k*3+1]-pb[i*3+1];
    float vz = pb[k*3+2]-pb[i*3+2];
    float r = sqrtf(vx*vx+vy*vy+vz*vz) + 1e-8f;
    float inv = 1.0f/r;
    if (jh == 0){ vhx[kk][i]=vx*inv; vhy[kk][i]=vy*inv; vhz[kk][i]=vz*inv; }
    float u = r*0.2f;
    float env = 0.0f;
    if (u < 1.0f && i != k){
      float u2=u*u, u6=u2*u2*u2;
      env = 1.0f - 28.0f*u6 + 48.0f*u6*u - 21.0f*u6*u2;
    }
    float coef = 0.6324555320336759f * inv * env;
    float th   = r * 0.6283185307179586f;
    float s1 = __sinf(th), c1 = __cosf(th);
    float rb[NB];
    rb[0] = coef*s1;
    float twoc = 2.f*c1, sp = s1, spp = 0.f;
    #pragma unroll
    for(int n=1;n<NB;n++){ float s = twoc*sp - spp; spp = sp; sp = s; rb[n] = coef*s; }
    u16* hrow = hidB[kk] + i*HSTRB;
    #pragma unroll
    for(int jg0=0;jg0<8;jg0++){
      const int jg = jh*8 + jg0;
      float h0=0.f,h1=0.f,h2=0.f,h3=0.f;
      #pragma unroll
      for(int n=0;n<NB;n++){
        const float* wr = Wr1l + n*HID + jg*4;
        float rn = rb[n];
        h0 = fmaf(rn, wr[0], h0);
        h1 = fmaf(rn, wr[1], h1);
        h2 = fmaf(rn, wr[2], h2);
        h3 = fmaf(rn, wr[3], h3);
      }
      ushort4 uu = make_ushort4(f2bf(silu_f(h0)), f2bf(silu_f(h1)),
                                f2bf(silu_f(h2)), f2bf(silu_f(h3)));
      *(ushort4*)(hrow + jg*4) = uu;
    }
    if (tid < 3){
      float a0=0.f, a1=0.f;
      for (int n=0;n<NN;n+=2){ a0 += pb[n*3+tid]; a1 += pb[(n+1)*3+tid]; }
      comL[tid] = (a0+a1) * (1.0f/128.0f);
    }
  }
  __syncthreads();

  const float* sIb = sIn + b*FS*NN;
  const float* vIb = vIn + b*FV*3*NN;
  const float* tIb = tIn + b*FV*NN;
  const int i00 = sh*64 + quad*4;

  // ---- fused MFMA phase: wave-half gh selects group set ----
  if (gh == 0){
    const int c_s0 = wq*16 + col;
    const int c_s1 = 64 + c_s0;

    const u16* wp0 = w2bl + c_s0*HID + quad*8;
    const u16* wp1 = w2bl + c_s1*HID + quad*8;
    const u16* wp2 = w2bl + (128 + c_s0)*HID + quad*8;
    const frag_ab b00 = *(const frag_ab*)(wp0), b01 = *(const frag_ab*)(wp0+32);
    const frag_ab b10 = *(const frag_ab*)(wp1), b11 = *(const frag_ab*)(wp1+32);
    const frag_ab b20 = *(const frag_ab*)(wp2), b21 = *(const frag_ab*)(wp2+32);

    const float* fs0 = sIb + c_s0*NN + i00;
    const float* fs1 = sIb + c_s1*NN + i00;
    const float* fv  = vIb + c_s0*3*NN + i00;

    float sA0[4]={0.f,0.f,0.f,0.f}, sA1[4]={0.f,0.f,0.f,0.f}, sA2[4]={0.f,0.f,0.f,0.f};

    #pragma unroll 1
    for (int mt=0; mt<4; mt++){
      float4 s4a = *(const float4*)&fs0[mt*16];
      float4 s4b = *(const float4*)&fs1[mt*16];
      float4 vx4 = *(const float4*)&fv[mt*16];
      float4 vy4 = *(const float4*)&fv[NN + mt*16];
      float4 vz4 = *(const float4*)&fv[2*NN + mt*16];
      const int hbase = (sh*64 + mt*16 + col)*HSTRB + quad*8;
      const int vbase = i00 + mt*16;
      #pragma unroll
      for (int kk=0; kk<4; kk++){
        frag_ab a0 = *(const frag_ab*)&hidB[kk][hbase];
        frag_ab a1 = *(const frag_ab*)&hidB[kk][hbase + 32];
        float4 hx4 = *(const float4*)&vhx[kk][vbase];
        float4 hy4 = *(const float4*)&vhy[kk][vbase];
        float4 hz4 = *(const float4*)&vhz[kk][vbase];
        frag_cd ac0 = {0.f,0.f,0.f,0.f};
        frag_cd ac1 = {0.f,0.f,0.f,0.f};
        frag_cd ac2 = {0.f,0.f,0.f,0.f};
        ac0 = __builtin_amdgcn_mfma_f32_16x16x32_bf16(a0, b00, ac0, 0,0,0);
        ac1 = __builtin_amdgcn_mfma_f32_16x16x32_bf16(a0, b10, ac1, 0,0,0);
        ac2 = __builtin_amdgcn_mfma_f32_16x16x32_bf16(a0, b20, ac2, 0,0,0);
        ac0 = __builtin_amdgcn_mfma_f32_16x16x32_bf16(a1, b01, ac0, 0,0,0);
        ac1 = __builtin_amdgcn_mfma_f32_16x16x32_bf16(a1, b11, ac1, 0,0,0);
        ac2 = __builtin_amdgcn_mfma_f32_16x16x32_bf16(a1, b21, ac2, 0,0,0);

        sA0[kk] += ac0[0]*s4a.x + ac0[1]*s4a.y + ac0[2]*s4a.z + ac0[3]*s4a.w;
        sA1[kk] += ac1[0]*s4b.x + ac1[1]*s4b.y + ac1[2]*s4b.z + ac1[3]*s4b.w;
        sA2[kk] += ac2[0]*(vx4.x*hx4.x + vy4.x*hy4.x + vz4.x*hz4.x)
                 + ac2[1]*(vx4.y*hx4.y + vy4.y*hy4.y + vz4.y*hz4.y)
                 + ac2[2]*(vx4.z*hx4.z + vy4.z*hy4.z + vz4.z*hz4.z)
                 + ac2[3]*(vx4.w*hx4.w + vy4.w*hy4.w + vz4.w*hz4.w);
      }
    }
    #pragma unroll
    for (int kk=0; kk<4; kk++){
      float v0 = sA0[kk]; v0 += __shfl_xor(v0,16,64); v0 += __shfl_xor(v0,32,64);
      float v1 = sA1[kk]; v1 += __shfl_xor(v1,16,64); v1 += __shfl_xor(v1,32,64);
      float v2 = sA2[kk]; v2 += __shfl_xor(v2,16,64); v2 += __shfl_xor(v2,32,64);
      if (lane < 16){
        aggP[kk][sh][wq*16 + lane]       = v0;
        aggP[kk][sh][64 + wq*16 + lane]  = v1;
        aggP[kk][sh][128 + wq*16 + lane] = v2;
      }
    }
  } else {
    const int f_vc = wq*16 + col;

    const u16* wp3 = w2bl + (192 + f_vc)*HID + quad*8;
    const u16* wp4 = w2bl + (256 + f_vc)*HID + quad*8;
    const frag_ab b30 = *(const frag_ab*)(wp3), b31 = *(const frag_ab*)(wp3+32);
    const frag_ab b40 = *(const frag_ab*)(wp4), b41 = *(const frag_ab*)(wp4+32);

    const float* fv = vIb + f_vc*3*NN + i00;
    const float* ft = tIb + f_vc*NN + i00;

    float sX3[4]={0.f,0.f,0.f,0.f}, sY3[4]={0.f,0.f,0.f,0.f}, sZ3[4]={0.f,0.f,0.f,0.f};
    float sX4[4]={0.f,0.f,0.f,0.f}, sY4[4]={0.f,0.f,0.f,0.f}, sZ4[4]={0.f,0.f,0.f,0.f};

    #pragma unroll 1
    for (int mt=0; mt<4; mt++){
      float4 vx4 = *(const float4*)&fv[mt*16];
      float4 vy4 = *(const float4*)&fv[NN + mt*16];
      float4 vz4 = *(const float4*)&fv[2*NN + mt*16];
      float4 t4  = *(const float4*)&ft[mt*16];
      const int hbase = (sh*64 + mt*16 + col)*HSTRB + quad*8;
      const int vbase = i00 + mt*16;
      #pragma unroll
      for (int kk=0; kk<4; kk++){
        frag_ab a0 = *(const frag_ab*)&hidB[kk][hbase];
        frag_ab a1 = *(const frag_ab*)&hidB[kk][hbase + 32];
        float4 hx4 = *(const float4*)&vhx[kk][vbase];
        float4 hy4 = *(const float4*)&vhy[kk][vbase];
        float4 hz4 = *(const float4*)&vhz[kk][vbase];
        frag_cd ac3 = {0.f,0.f,0.f,0.f};
        frag_cd ac4 = {0.f,0.f,0.f,0.f};
        ac3 = __builtin_amdgcn_mfma_f32_16x16x32_bf16(a0, b30, ac3, 0,0,0);
        ac4 = __builtin_amdgcn_mfma_f32_16x16x32_bf16(a0, b40, ac4, 0,0,0);
        ac3 = __builtin_amdgcn_mfma_f32_16x16x32_bf16(a1, b31, ac3, 0,0,0);
        ac4 = __builtin_amdgcn_mfma_f32_16x16x32_bf16(a1, b41, ac4, 0,0,0);

        float t0_ = ac3[0]*t4.x, t1_ = ac3[1]*t4.y, t2_ = ac3[2]*t4.z, t3_ = ac3[3]*t4.w;
        sX3[kk] += t0_*hx4.x + t1_*hx4.y + t2_*hx4.z + t3_*hx4.w;
        sY3[kk] += t0_*hy4.x + t1_*hy4.y + t2_*hy4.z + t3_*hy4.w;
        sZ3[kk] += t0_*hz4.x + t1_*hz4.y + t2_*hz4.z + t3_*hz4.w;
        sX4[kk] += ac4[0]*vx4.x + ac4[1]*vx4.y + ac4[2]*vx4.z + ac4[3]*vx4.w;
        sY4[kk] += ac4[0]*vy4.x + ac4[1]*vy4.y + ac4[2]*vy4.z + ac4[3]*vy4.w;
        sZ4[kk] += ac4[0]*vz4.x + ac4[1]*vz4.y + ac4[2]*vz4.z + ac4[3]*vz4.w;
      }
    }
    #pragma unroll
    for (int kk=0; kk<4; kk++){
      float x3 = sX3[kk]; x3 += __shfl_xor(x3,16,64); x3 += __shfl_xor(x3,32,64);
      float y3 = sY3[kk]; y3 += __shfl_xor(y3,16,64); y3 += __shfl_xor(y3,32,64);
      float z3 = sZ3[kk]; z3 += __shfl_xor(z3,16,64); z3 += __shfl_xor(z3,32,64);
      float x4 = sX4[kk]; x4 += __shfl_xor(x4,16,64); x4 += __shfl_xor(x4,32,64);
      float y4 = sY4[kk]; y4 += __shfl_xor(y4,16,64); y4 += __shfl_xor(y4,32,64);
      float z4 = sZ4[kk]; z4 += __shfl_xor(z4,16,64); z4 += __shfl_xor(z4,32,64);
      if (lane < 16){
        const int f2 = wq*16 + lane;
        aggP[kk][sh][192       + f2] = x3;
        aggP[kk][sh][192 +  68 + f2] = y3;
        aggP[kk][sh][192 + 136 + f2] = z3;
        aggP[kk][sh][396       + f2] = x4;
        aggP[kk][sh][396 +  68 + f2] = y4;
        aggP[kk][sh][396 + 136 + f2] = z4;
      }
    }
  }

  __syncthreads();
  for (int t2=tid; t2<2400; t2+=1024){
    const int kk = t2 / 600;
    const int t  = t2 - kk*600;
    aggP[kk][0][t] = (aggP[kk][0][t] + aggP[kk][1][t]) * (1.0f/128.0f);
  }
  __syncthreads();

  // ---- E1: s-mix 4-way partials (tid<512) | V-mix (tid 512..703) ----
  if (tid < 512){
    const int o = tid & 127, p = tid >> 7;
    const int c0 = p*48;
    float a0=0.f,a1=0.f,a2=0.f,a3=0.f;
    #pragma unroll 2
    for (int cc=c0; cc<c0+48; cc+=4){
      float4 g0 = *(const float4*)&aggP[0][0][cc];
      float4 g1 = *(const float4*)&aggP[1][0][cc];
      float4 g2 = *(const float4*)&aggP[2][0][cc];
      float4 g3 = *(const float4*)&aggP[3][0][cc];
      float w0 = WmixSl[cc*FS+o];
      float w1 = WmixSl[(cc+1)*FS+o];
      float w2 = WmixSl[(cc+2)*FS+o];
      float w3 = WmixSl[(cc+3)*FS+o];
      a0 = fmaf(g0.x,w0,a0); a0 = fmaf(g0.y,w1,a0); a0 = fmaf(g0.z,w2,a0); a0 = fmaf(g0.w,w3,a0);
      a1 = fmaf(g1.x,w0,a1); a1 = fmaf(g1.y,w1,a1); a1 = fmaf(g1.z,w2,a1); a1 = fmaf(g1.w,w3,a1);
      a2 = fmaf(g2.x,w0,a2); a2 = fmaf(g2.y,w1,a2); a2 = fmaf(g2.z,w2,a2); a2 = fmaf(g2.w,w3,a2);
      a3 = fmaf(g3.x,w0,a3); a3 = fmaf(g3.y,w1,a3); a3 = fmaf(g3.z,w2,a3); a3 = fmaf(g3.w,w3,a3);
    }
    sPart[0][p][o] = a0; sPart[1][p][o] = a1;
    sPart[2][p][o] = a2; sPart[3][p][o] = a3;
  } else if (tid < 704){
    const int o = tid - 512;            // 0..191
    const int c3 = o >> 6, g = o & 63;
    float a0=0.f,a1=0.f,a2=0.f,a3=0.f;
    #pragma unroll 1
    for (int f0=0; f0<FV; f0+=4){
      float4 p0 = *(const float4*)&aggP[0][0][192+c3*68+f0];
      float4 q0 = *(const float4*)&aggP[0][0][396+c3*68+f0];
      float4 p1 = *(const float4*)&aggP[1][0][192+c3*68+f0];
      float4 q1 = *(const float4*)&aggP[1][0][396+c3*68+f0];
      float4 p2 = *(const float4*)&aggP[2][0][192+c3*68+f0];
      float4 q2 = *(const float4*)&aggP[2][0][396+c3*68+f0];
      float4 p3 = *(const float4*)&aggP[3][0][192+c3*68+f0];
      float4 q3 = *(const float4*)&aggP[3][0][396+c3*68+f0];
      float w00 = WmixVl[f0*FV+g];
      float w01 = WmixVl[(f0+1)*FV+g];
      float w02 = WmixVl[(f0+2)*FV+g];
      float w03 = WmixVl[(f0+3)*FV+g];
      float w10 = WmixVl[(f0+FV)*FV+g];
      float w11 = WmixVl[(f0+FV+1)*FV+g];
      float w12 = WmixVl[(f0+FV+2)*FV+g];
      float w13 = WmixVl[(f0+FV+3)*FV+g];
      a0 = fmaf(p0.x,w00,a0); a0 = fmaf(p0.y,w01,a0); a0 = fmaf(p0.z,w02,a0); a0 = fmaf(p0.w,w03,a0);
      a0 = fmaf(q0.x,w10,a0); a0 = fmaf(q0.y,w11,a0); a0 = fmaf(q0.z,w12,a0); a0 = fmaf(q0.w,w13,a0);
      a1 = fmaf(p1.x,w00,a1); a1 = fmaf(p1.y,w01,a1); a1 = fmaf(p1.z,w02,a1); a1 = fmaf(p1.w,w03,a1);
      a1 = fmaf(q1.x,w10,a1); a1 = fmaf(q1.y,w11,a1); a1 = fmaf(q1.z,w12,a1); a1 = fmaf(q1.w,w13,a1);
      a2 = fmaf(p2.x,w00,a2); a2 = fmaf(p2.y,w01,a2); a2 = fmaf(p2.z,w02,a2); a2 = fmaf(p2.w,w03,a2);
      a2 = fmaf(q2.x,w10,a2); a2 = fmaf(q2.y,w11,a2); a2 = fmaf(q2.z,w12,a2); a2 = fmaf(q2.w,w13,a2);
      a3 = fmaf(p3.x,w00,a3); a3 = fmaf(p3.y,w01,a3); a3 = fmaf(p3.z,w02,a3); a3 = fmaf(p3.w,w03,a3);
      a3 = fmaf(q3.x,w10,a3); a3 = fmaf(q3.y,w11,a3); a3 = fmaf(q3.z,w12,a3); a3 = fmaf(q3.w,w13,a3);
    }
    const int oo = g*3 + c3;
    vNewL[0][c3*68+g] = vIb[oo*NN + k0]     + a0;
    vNewL[1][c3*68+g] = vIb[oo*NN + k0 + 1] + a1;
    vNewL[2][c3*68+g] = vIb[oo*NN + k0 + 2] + a2;
    vNewL[3][c3*68+g] = vIb[oo*NN + k0 + 3] + a3;
  }
  __syncthreads();

  // ---- E2: s-finalize (tid<128) | out_v (tid 128..319) ----
  if (tid < FS){
    #pragma unroll
    for (int kk=0; kk<4; kk++)
      sNew[kk][tid] = sIb[tid*NN + k0 + kk]
                    + silu_f(sPart[kk][0][tid] + sPart[kk][1][tid]
                           + sPart[kk][2][tid] + sPart[kk][3][tid]);
  } else if (tid < 320){
    const int o = tid - 128;
    const int g = o/3, c3 = o - g*3;
    float a0 = comL[c3], a1 = comL[c3], a2 = comL[c3], a3 = comL[c3];
    #pragma unroll 2
    for (int f0=0; f0<FV; f0+=4){
      float4 v0 = *(const float4*)&vNewL[0][c3*68+f0];
      float4 v1 = *(const float4*)&vNewL[1][c3*68+f0];
      float4 v2 = *(const float4*)&vNewL[2][c3*68+f0];
      float4 v3 = *(const float4*)&vNewL[3][c3*68+f0];
      float w0 = WoutV[f0*FV+g];
      float w1 = WoutV[(f0+1)*FV+g];
      float w2 = WoutV[(f0+2)*FV+g];
      float w3 = WoutV[(f0+3)*FV+g];
      a0 = fmaf(v0.x,w0,a0); a0 = fmaf(v0.y,w1,a0); a0 = fmaf(v0.z,w2,a0); a0 = fmaf(v0.w,w3,a0);
      a1 = fmaf(v1.x,w0,a1); a1 = fmaf(v1.y,w1,a1); a1 = fmaf(v1.z,w2,a1); a1 = fmaf(v1.w,w3,a1);
      a2 = fmaf(v2.x,w0,a2); a2 = fmaf(v2.y,w1,a2); a2 = fmaf(v2.z,w2,a2); a2 = fmaf(v2.w,w3,a2);
      a3 = fmaf(v3.x,w0,a3); a3 = fmaf(v3.y,w1,a3); a3 = fmaf(v3.z,w2,a3); a3 = fmaf(v3.w,w3,a3);
    }
    outp[(b*NN+k0)*FV*3 + o]   = a0;
    outp[(b*NN+k0+1)*FV*3 + o] = a1;
    outp[(b*NN+k0+2)*FV*3 + o] = a2;
    outp[(b*NN+k0+3)*FV*3 + o] = a3;
  }
  __syncthreads();

  // ---- E3a: out_s 4-way f-partials into dead aggP scratch (tid<512) ----
  float* e3s = &aggP[0][0][0];   // 4800 floats free after E1; need 2048
  if (tid < 512){
    const int o = tid & 127, p = tid >> 7;
    const int f0 = p*32;
    float a0=0.f,a1=0.f,a2=0.f,a3=0.f;
    #pragma unroll 2
    for (int f=f0; f<f0+32; f+=4){
      float4 s0 = *(const float4*)&sNew[0][f];
      float4 s1 = *(const float4*)&sNew[1][f];
      float4 s2 = *(const float4*)&sNew[2][f];
      float4 s3 = *(const float4*)&sNew[3][f];
      float w0 = WoutS[f*FS+o];
      float w1 = WoutS[(f+1)*FS+o];
      float w2 = WoutS[(f+2)*FS+o];
      float w3 = WoutS[(f+3)*FS+o];
      a0 = fmaf(s0.x,w0,a0); a0 = fmaf(s0.y,w1,a0); a0 = fmaf(s0.z,w2,a0); a0 = fmaf(s0.w,w3,a0);
      a1 = fmaf(s1.x,w0,a1); a1 = fmaf(s1.y,w1,a1); a1 = fmaf(s1.z,w2,a1); a1 = fmaf(s1.w,w3,a1);
      a2 = fmaf(s2.x,w0,a2); a2 = fmaf(s2.y,w1,a2); a2 = fmaf(s2.z,w2,a2); a2 = fmaf(s2.w,w3,a2);
      a3 = fmaf(s3.x,w0,a3); a3 = fmaf(s3.y,w1,a3); a3 = fmaf(s3.z,w2,a3); a3 = fmaf(s3.w,w3,a3);
    }
    e3s[(p*4+0)*128 + o] = a0;
    e3s[(p*4+1)*128 + o] = a1;
    e3s[(p*4+2)*128 + o] = a2;
    e3s[(p*4+3)*128 + o] = a3;
  }
  __syncthreads();

  // ---- E3b: combine partials and write out_s ----
  if (tid < 512){
    const int o = tid & 127, kk = tid >> 7;
    float a = e3s[(0*4+kk)*128 + o] + e3s[(1*4+kk)*128 + o]
            + e3s[(2*4+kk)*128 + o] + e3s[(3*4+kk)*128 + o];
    outp[BATCH*NN*FV*3 + (b*NN+k0+kk)*FS + o] = a;
  }
}

extern "C" void kernel_launch(void* const* d_in, const int* in_sizes, int n_in,
                              void* d_out, int out_size, void* d_ws, size_t ws_size,
                              hipStream_t stream)
{
  const float* x       = (const float*)d_in[0];
  const float* species = (const float*)d_in[1];
  const float* Wr1     = (const float*)d_in[2];
  const float* Wr2     = (const float*)d_in[3];
  const float* Wsv     = (const float*)d_in[4];
  const float* WmixS   = (const float*)d_in[5];
  const float* WmixV   = (const float*)d_in[6];
  const float* WoutS   = (const float*)d_in[7];
  const float* WoutV   = (const float*)d_in[8];
  float* ws  = (float*)d_ws;
  float* out = (float*)d_out;

  float* sB  = ws + OFF_SB;
  float* vB  = ws + OFF_VB;
  float* t1  = ws + OFF_T1;
  u16*   w2b = (u16*)(ws + OFF_W2B);

  // layer 0 (specialized, 2 receivers/block) -> sB, vB, t1; also Wr2[layer1] -> w2b bf16
  layer0_kernel<<<BATCH*NN/2, 512, 0, stream>>>(x, species, Wr1, Wr2, Wsv,
      WmixS, WmixV, sB, vB, t1, w2b);

  // layer 1 (final, 4 receivers/block, 1024 threads): writes d_out directly
  layer_kernel<<<BATCH*NN/4, 1024, 0, stream>>>(x, sB, vB, t1,
      Wr1 + NB*HID, w2b, WmixS + 192*FS, WmixV + 128*FV,
      WoutS, WoutV, out);
}